// Round 1
// 690.030 us; speedup vs baseline: 1.0333x; 1.0333x over previous
//
#include <hip/hip_runtime.h>
#include <hip/hip_bf16.h>
#include <math.h>

typedef unsigned short u16;
typedef unsigned int   u32;
typedef _Float16 f16x8 __attribute__((ext_vector_type(8)));
typedef float f32x4  __attribute__((ext_vector_type(4)));

#define Bb 32
#define Tt 2048
#define Ee 1024
#define Mm (Bb*Tt)

__device__ __forceinline__ float tanh_fast(float x) {
  float ax = fminf(fabsf(x), 15.0f);
  float e  = __expf(2.0f * ax);
  float t  = 1.0f - 2.0f / (e + 1.0f);
  return copysignf(t, x);
}

__device__ __forceinline__ u32 pack2h(float a, float b) {
  _Float16 ha = (_Float16)a, hb = (_Float16)b;   // v_cvt_f16_f32 (RTN) — numerics preserved
  return (u32)__builtin_bit_cast(u16, ha) | ((u32)__builtin_bit_cast(u16, hb) << 16);
}

// async global->LDS, 16B per lane; LDS dest is wave-uniform base + lane*16
__device__ __forceinline__ void glds16(const u16* g, u16* l) {
  __builtin_amdgcn_global_load_lds(
      (const __attribute__((address_space(1))) void*)g,
      (__attribute__((address_space(3))) void*)l, 16, 0, 0);
}

// ---------------- K0: W (K x N fp32) -> Wt_hi/Wt_lo (N x K fp16 split) ----------------
__global__ __launch_bounds__(256) void wt_convert(const float* __restrict__ W,
                                                  u16* __restrict__ Wt_hi,
                                                  u16* __restrict__ Wt_lo) {
  __shared__ float tile[32][33];
  int n0 = blockIdx.x * 32, k0 = blockIdx.y * 32;
  int tx = threadIdx.x, ty = threadIdx.y;   // 32 x 8
#pragma unroll
  for (int i = 0; i < 4; ++i)
    tile[ty + 8*i][tx] = W[(size_t)(k0 + ty + 8*i) * Ee + n0 + tx];
  __syncthreads();
#pragma unroll
  for (int i = 0; i < 4; ++i) {
    float v = tile[tx][ty + 8*i];
    _Float16 hi = (_Float16)v;
    float rem = v - (float)hi;
    _Float16 lo = (_Float16)rem;
    size_t idx = (size_t)(n0 + ty + 8*i) * Ee + k0 + tx;
    Wt_hi[idx] = __builtin_bit_cast(u16, hi);
    Wt_lo[idx] = __builtin_bit_cast(u16, lo);
  }
}

// ---------------- K1: ht = tanh(enc@W + b), fused score = ctx . ht ----------------
// 128x128 tile, BK=32, issue-early/consume-late pipeline (T3 minimum 2-phase):
//   top of iter kt: issue A f32 loads (kt+1) + B global_load_lds (kt+1 -> buf^1)
//   middle:         ds_read frags (buf) + 32 MFMA under setprio(1)
//   bottom:         pack A -> ds_write (buf^1); one barrier (drains vm+lgkm)
// LDS: unpadded [128][32] f16 planes, 16B-chunk XOR swizzle
//   phys_chunk = logical_chunk ^ ((row>>1)&3)  -> reads AND writes at the
//   32-bank BW floor (8 lanes per 4-bank group, all groups distinct).
// B planes are staged with global_load_lds (linear LDS dest) by pre-swizzling
// the per-lane GLOBAL source chunk (guide §5 caveat / m173 pattern).
__global__ __launch_bounds__(256, 3) void gemm_tanh_score(
    const float* __restrict__ enc, const float* __restrict__ ctx,
    const float* __restrict__ bias,
    const u16* __restrict__ Wt_hi, const u16* __restrict__ Wt_lo,
    u16* __restrict__ ht, float* __restrict__ scores) {
  // 2 buffers x 3 planes x 8KB = 48KB -> 3 blocks/CU
  __shared__ __align__(16) u16 Ah[2*4096];
  __shared__ __align__(16) u16 BhS[2*4096];
  __shared__ __align__(16) u16 BlS[2*4096];

  int bx = blockIdx.x;
  // XCD-grouped swizzle: xcd = bx&7 owns mt in [xcd*64, xcd*64+64); within an
  // XCD the 8 nt-blocks of one mt-panel are consecutive -> enc panel fetched
  // once chip-wide; the 8 W column-panels (4MB hi+lo) stay L2-resident.
  int xcd = bx & 7, lb = bx >> 3;
  int nt = lb & 7, mtl = lb >> 3;
  int mt = xcd * 64 + mtl;
  int m0 = mt * 128, n0 = nt * 128;

  int tid = threadIdx.x;
  int w = tid >> 6, lane = tid & 63;
  int wm = (w & 1) * 64, wn = (w >> 1) * 64;
  int q = lane >> 4, c = lane & 15;
  int fch = (q ^ ((c >> 1) & 3)) * 8;   // frag phys-chunk offset (u16 units)

  f32x4 zero = {0.f, 0.f, 0.f, 0.f};
  f32x4 acc[4][4];
#pragma unroll
  for (int i = 0; i < 4; ++i)
#pragma unroll
    for (int j = 0; j < 4; ++j) acc[i][j] = zero;

  // ---- A staging map (reg path: fp32 -> fp16 pack) ----
  int ar = tid >> 1, ah = tid & 1;                  // row 0..127, k-half
  const float4* Abase = (const float4*)(enc + (size_t)(m0 + ar) * Ee + ah * 16);
  int awr = ar * 32;
  int asw = (ar >> 1) & 3;
  int ac0 = ((2*ah + 0) ^ asw) * 8;
  int ac1 = ((2*ah + 1) ^ asw) * 8;

  // ---- B staging map (global_load_lds, pre-swizzled source) ----
  // wave w fills 1KB chunks cidx = 2w, 2w+1 of each 8KB plane; lane covers
  // phys byte X = cidx*1024 + lane*16 -> row = X>>6, phys chunk = (X>>4)&3
  int cidx0 = w * 2, cidx1 = w * 2 + 1;
  int r0 = cidx0 * 16 + (lane >> 2);
  int r1 = cidx1 * 16 + (lane >> 2);
  int lg0 = ((lane & 3) ^ ((r0 >> 1) & 3)) * 8;     // logical chunk -> source offset
  int lg1 = ((lane & 3) ^ ((r1 >> 1) & 3)) * 8;
  const u16* Bh0 = Wt_hi + (size_t)(n0 + r0) * Ee + lg0;
  const u16* Bh1 = Wt_hi + (size_t)(n0 + r1) * Ee + lg1;
  const u16* Bl0 = Wt_lo + (size_t)(n0 + r0) * Ee + lg0;
  const u16* Bl1 = Wt_lo + (size_t)(n0 + r1) * Ee + lg1;
  int bws0 = cidx0 * 512, bws1 = cidx1 * 512;       // u16 LDS offsets (wave-uniform)

  // ---- prologue: stage kt=0 into buffer 0 ----
  {
    float4 f0 = Abase[0], f1 = Abase[1], f2 = Abase[2], f3 = Abase[3];
    glds16(Bh0, &BhS[bws0]);
    glds16(Bh1, &BhS[bws1]);
    glds16(Bl0, &BlS[bws0]);
    glds16(Bl1, &BlS[bws1]);
    u32 p0 = pack2h(f0.x, f0.y), p1 = pack2h(f0.z, f0.w);
    u32 p2 = pack2h(f1.x, f1.y), p3 = pack2h(f1.z, f1.w);
    u32 p4 = pack2h(f2.x, f2.y), p5 = pack2h(f2.z, f2.w);
    u32 p6 = pack2h(f3.x, f3.y), p7 = pack2h(f3.z, f3.w);
    *(uint4*)&Ah[awr + ac0] = make_uint4(p0, p1, p2, p3);
    *(uint4*)&Ah[awr + ac1] = make_uint4(p4, p5, p6, p7);
    __syncthreads();   // drains vmcnt(0)+lgkmcnt(0): buffer 0 ready
  }

#pragma unroll 2
  for (int kt = 0; kt < 32; ++kt) {
    int cur = (kt & 1) * 4096, nxt = 4096 - cur;
    float4 f0, f1, f2, f3;
    if (kt < 31) {
      // issue next tile's loads BEFORE this tile's MFMAs (latency hides under compute)
      const float4* ap = Abase + (size_t)(kt + 1) * 8;
      f0 = ap[0]; f1 = ap[1]; f2 = ap[2]; f3 = ap[3];
      size_t ko = (size_t)(kt + 1) * 32;
      glds16(Bh0 + ko, &BhS[nxt + bws0]);
      glds16(Bh1 + ko, &BhS[nxt + bws1]);
      glds16(Bl0 + ko, &BlS[nxt + bws0]);
      glds16(Bl1 + ko, &BlS[nxt + bws1]);
    }

    f16x8 aF[4];
#pragma unroll
    for (int i = 0; i < 4; ++i)
      aF[i] = *(const f16x8*)&Ah[cur + (wm + i*16 + c) * 32 + fch];

    __builtin_amdgcn_s_setprio(1);
#pragma unroll
    for (int j = 0; j < 4; ++j) {
      f16x8 bH = *(const f16x8*)&BhS[cur + (wn + j*16 + c) * 32 + fch];
      f16x8 bL = *(const f16x8*)&BlS[cur + (wn + j*16 + c) * 32 + fch];
#pragma unroll
      for (int i = 0; i < 4; ++i) {
        acc[i][j] = __builtin_amdgcn_mfma_f32_16x16x32_f16(aF[i], bH, acc[i][j], 0, 0, 0);
        acc[i][j] = __builtin_amdgcn_mfma_f32_16x16x32_f16(aF[i], bL, acc[i][j], 0, 0, 0);
      }
    }
    __builtin_amdgcn_s_setprio(0);

    if (kt < 31) {
      // consume the early A loads (compiler inserts the counted vmcnt wait)
      u32 p0 = pack2h(f0.x, f0.y), p1 = pack2h(f0.z, f0.w);
      u32 p2 = pack2h(f1.x, f1.y), p3 = pack2h(f1.z, f1.w);
      u32 p4 = pack2h(f2.x, f2.y), p5 = pack2h(f2.z, f2.w);
      u32 p6 = pack2h(f3.x, f3.y), p7 = pack2h(f3.z, f3.w);
      *(uint4*)&Ah[nxt + awr + ac0] = make_uint4(p0, p1, p2, p3);
      *(uint4*)&Ah[nxt + awr + ac1] = make_uint4(p4, p5, p6, p7);
    }
    // single barrier per K-step: drains B glds (vmcnt) + A ds_writes (lgkm);
    // safe: a wave can only touch buf^1 after ALL waves passed the previous
    // barrier, i.e. after all reads of buf^1 retired.
    __syncthreads();
  }

  // epilogue: z -> tanh -> store bf16 ht; fused score partial (ctx dot)
  int bidx = m0 >> 11;                   // T = 2048, tile rows share one batch index
  float ctxv[4], biasv[4];
#pragma unroll
  for (int j = 0; j < 4; ++j) {
    int col = n0 + wn + j * 16 + c;
    ctxv[j]  = ctx[bidx * Ee + col];
    biasv[j] = bias[col];
  }
#pragma unroll
  for (int i = 0; i < 4; ++i) {
#pragma unroll
    for (int r = 0; r < 4; ++r) {
      int rowG = m0 + wm + i * 16 + q * 4 + r;   // C/D: row=(lane>>4)*4+reg, col=lane&15
      u16* hrow = ht + (size_t)rowG * Ee + n0 + wn + c;
      float s = 0.f;
#pragma unroll
      for (int j = 0; j < 4; ++j) {
        float h = tanh_fast(acc[i][j][r] + biasv[j]);
        __hip_bfloat16 hb = __float2bfloat16(h);
        hrow[j * 16] = *(u16*)&hb;
        s += h * ctxv[j];
      }
      s += __shfl_xor(s, 1); s += __shfl_xor(s, 2);
      s += __shfl_xor(s, 4); s += __shfl_xor(s, 8);
      if (c == 0) atomicAdd(&scores[rowG], s);
    }
  }
}

// ---------------- K2: softmax over T per batch row ----------------
__global__ __launch_bounds__(256) void softmax_t(const float* __restrict__ scores,
                                                 float* __restrict__ at) {
  __shared__ float red[256];
  int b = blockIdx.x, tid = threadIdx.x;
  float v[8];
  float mx = -3.0e38f;
#pragma unroll
  for (int i = 0; i < 8; ++i) {
    v[i] = scores[b * Tt + i * 256 + tid];
    mx = fmaxf(mx, v[i]);
  }
  red[tid] = mx; __syncthreads();
  for (int s = 128; s > 0; s >>= 1) {
    if (tid < s) red[tid] = fmaxf(red[tid], red[tid + s]);
    __syncthreads();
  }
  mx = red[0]; __syncthreads();
  float sum = 0.f;
#pragma unroll
  for (int i = 0; i < 8; ++i) { v[i] = __expf(v[i] - mx); sum += v[i]; }
  red[tid] = sum; __syncthreads();
  for (int s = 128; s > 0; s >>= 1) {
    if (tid < s) red[tid] += red[tid + s];
    __syncthreads();
  }
  float inv = 1.0f / red[0];
#pragma unroll
  for (int i = 0; i < 8; ++i) at[b * Tt + i * 256 + tid] = v[i] * inv;
}

// ---------------- K3: partial[b,tc,e] = sum_{t in chunk} at[b,t] * ht[b,t,e] ----------------
__global__ __launch_bounds__(256) void weighted_sum(const u16* __restrict__ ht,
                                                    const float* __restrict__ at,
                                                    float* __restrict__ part) {
  __shared__ float ats[64];
  int bx = blockIdx.x;
  int b = bx >> 5, tc = bx & 31;
  int tid = threadIdx.x;
  if (tid < 64) ats[tid] = at[b * Tt + tc * 64 + tid];
  __syncthreads();
  int e0 = tid * 4;
  const u16* base = ht + (size_t)(b * Tt + tc * 64) * Ee + e0;
  float s0 = 0.f, s1 = 0.f, s2 = 0.f, s3 = 0.f;
#pragma unroll 4
  for (int t = 0; t < 64; ++t) {
    float a = ats[t];
    uint2 u = *(const uint2*)(base + (size_t)t * Ee);
    s0 += a * __uint_as_float(u.x << 16);
    s1 += a * __uint_as_float(u.x & 0xffff0000u);
    s2 += a * __uint_as_float(u.y << 16);
    s3 += a * __uint_as_float(u.y & 0xffff0000u);
  }
  float4 out4 = make_float4(s0, s1, s2, s3);
  *(float4*)(part + ((size_t)(b * 32 + tc) * Ee + e0)) = out4;
}

// ---------------- K4: out[b,e] = sum_tc part[b,tc,e] ----------------
__global__ __launch_bounds__(256) void reduce_part(const float* __restrict__ part,
                                                   float* __restrict__ out) {
  int b = blockIdx.x, tid = threadIdx.x;
  float4 s = make_float4(0.f, 0.f, 0.f, 0.f);
#pragma unroll
  for (int tc = 0; tc < 32; ++tc) {
    float4 p = ((const float4*)(part + (size_t)(b * 32 + tc) * Ee))[tid];
    s.x += p.x; s.y += p.y; s.z += p.z; s.w += p.w;
  }
  ((float4*)(out + (size_t)b * Ee))[tid] = s;
}

extern "C" void kernel_launch(void* const* d_in, const int* in_sizes, int n_in,
                              void* d_out, int out_size, void* d_ws, size_t ws_size,
                              hipStream_t stream) {
  const float* enc  = (const float*)d_in[0];
  const float* ctx  = (const float*)d_in[1];
  const float* W    = (const float*)d_in[2];
  const float* bias = (const float*)d_in[3];
  float* out = (float*)d_out;

  char* ws = (char*)d_ws;
  u16* Wt_hi = (u16*)(ws);
  u16* Wt_lo = (u16*)(ws + (size_t)2 * 1024 * 1024);
  u16* ht    = (u16*)(ws + (size_t)4 * 1024 * 1024);
  float* scores = (float*)(ws + (size_t)4 * 1024 * 1024 + (size_t)Mm * Ee * 2);
  float* at     = scores + Mm;
  // part reuses the Wt region (dead after the GEMM): 32*32*1024 fp32 = 4 MB
  float* part   = (float*)ws;

  hipMemsetAsync(scores, 0, (size_t)Mm * sizeof(float), stream);

  wt_convert<<<dim3(32, 32), dim3(32, 8), 0, stream>>>(W, Wt_hi, Wt_lo);
  gemm_tanh_score<<<dim3(4096), dim3(256), 0, stream>>>(enc, ctx, bias, Wt_hi, Wt_lo, ht, scores);
  softmax_t<<<dim3(32), dim3(256), 0, stream>>>(scores, at);
  weighted_sum<<<dim3(1024), dim3(256), 0, stream>>>(ht, at, part);
  reduce_part<<<dim3(32), dim3(256), 0, stream>>>(part, out);
}

// Round 2
// 651.988 us; speedup vs baseline: 1.0936x; 1.0583x over previous
//
#include <hip/hip_runtime.h>
#include <hip/hip_bf16.h>
#include <math.h>

typedef unsigned short u16;
typedef unsigned int   u32;
typedef _Float16 f16x8 __attribute__((ext_vector_type(8)));
typedef float f32x4  __attribute__((ext_vector_type(4)));

#define Bb 32
#define Tt 2048
#define Ee 1024
#define Mm (Bb*Tt)

__device__ __forceinline__ float tanh_fast(float x) {
  float ax = fminf(fabsf(x), 15.0f);
  float e  = __expf(2.0f * ax);
  float t  = 1.0f - 2.0f / (e + 1.0f);
  return copysignf(t, x);
}

__device__ __forceinline__ u32 pack2h(float a, float b) {
  _Float16 ha = (_Float16)a, hb = (_Float16)b;   // v_cvt_f16_f32 (RTN) — numerics preserved
  return (u32)__builtin_bit_cast(u16, ha) | ((u32)__builtin_bit_cast(u16, hb) << 16);
}

// async global->LDS, 16B per lane; LDS dest is wave-uniform base + lane*16
__device__ __forceinline__ void glds16(const u16* g, u16* l) {
  __builtin_amdgcn_global_load_lds(
      (const __attribute__((address_space(1))) void*)g,
      (__attribute__((address_space(3))) void*)l, 16, 0, 0);
}

// ---------------- K0: W (K x N fp32) -> Wt_hi/Wt_lo (N x K fp16 split) ----------------
__global__ __launch_bounds__(256) void wt_convert(const float* __restrict__ W,
                                                  u16* __restrict__ Wt_hi,
                                                  u16* __restrict__ Wt_lo) {
  __shared__ float tile[32][33];
  int n0 = blockIdx.x * 32, k0 = blockIdx.y * 32;
  int tx = threadIdx.x, ty = threadIdx.y;   // 32 x 8
#pragma unroll
  for (int i = 0; i < 4; ++i)
    tile[ty + 8*i][tx] = W[(size_t)(k0 + ty + 8*i) * Ee + n0 + tx];
  __syncthreads();
#pragma unroll
  for (int i = 0; i < 4; ++i) {
    float v = tile[tx][ty + 8*i];
    _Float16 hi = (_Float16)v;
    float rem = v - (float)hi;
    _Float16 lo = (_Float16)rem;
    size_t idx = (size_t)(n0 + ty + 8*i) * Ee + k0 + tx;
    Wt_hi[idx] = __builtin_bit_cast(u16, hi);
    Wt_lo[idx] = __builtin_bit_cast(u16, lo);
  }
}

// ---------------- K1: ht = tanh(enc@W + b), fused score = ctx . ht ----------------
// 256x128 tile, BK=32, 4 waves x wave-tile 128x64 (8 M-frags x 4 N-frags).
// Rationale (round-1 post-mortem): kernel was LDS-BW-bound (hi/lo doubles B
// read traffic). Growing the wave M-tile amortizes the doubled B operand:
// LDS traffic drops 57 -> 23 B/kFLOP; MFMA (1242 cyc/blk/step) now exceeds
// LDS (1129 cyc). Pipeline: issue kt+1 loads (A->regs coalesced, B->LDS via
// global_load_lds) before kt's MFMAs; pack/write A after; one barrier/step.
// LDS 16B-chunk XOR swizzle (phys = logical ^ ((row>>1)&3)): reads and
// writes verified uniform across banks (round-1 measured 0 conflicts).
__global__ __launch_bounds__(256, 2) void gemm_tanh_score(
    const float* __restrict__ enc, const float* __restrict__ ctx,
    const float* __restrict__ bias,
    const u16* __restrict__ Wt_hi, const u16* __restrict__ Wt_lo,
    u16* __restrict__ ht, float* __restrict__ scores) {
  // A: 2 x 16KB, Bhi/Blo: 2 x 8KB each -> 64KB total, 2 blocks/CU
  __shared__ __align__(16) u16 Ah [2*8192];
  __shared__ __align__(16) u16 BhS[2*4096];
  __shared__ __align__(16) u16 BlS[2*4096];

  int bx = blockIdx.x;
  // XCD-grouped swizzle: xcd owns a contiguous mt range; nt iterates fastest
  // so the 8 blocks sharing an enc panel run on the SAME XCD's L2.
  int xcd = bx & 7, lb = bx >> 3;
  int nt = lb & 7, mtl = lb >> 3;          // nt 0..7, mtl 0..31
  int mt = xcd * 32 + mtl;
  int m0 = mt * 256, n0 = nt * 128;

  int tid = threadIdx.x;
  int w = tid >> 6, lane = tid & 63;
  int wm = (w & 1) * 128, wn = (w >> 1) * 64;
  int q = lane >> 4, c = lane & 15;
  int fch = (q ^ ((c >> 1) & 3)) * 8;      // frag phys-chunk offset (u16 units)

  f32x4 zero = {0.f, 0.f, 0.f, 0.f};
  f32x4 acc[8][4];
#pragma unroll
  for (int i = 0; i < 8; ++i)
#pragma unroll
    for (int j = 0; j < 4; ++j) acc[i][j] = zero;

  // ---- A staging map (coalesced: 8 threads cover one 32-f32 row) ----
  // thread t: base row = t>>3 (+32 per pass p=0..7), 16B chunk = t&7.
  // Global: lanes 0..7 read 128 contiguous bytes of one row -> fully coalesced.
  // LDS: packed 8B half-chunk at swizzled offset (compile-time imm per pass).
  int arow = tid >> 3, ac8 = tid & 7;
  const float4* Abase = (const float4*)enc + ((size_t)(m0 + arow) * Ee >> 2) + ac8;
  // ((arow+32p)>>1)&3 == (arow>>1)&3 since 16p % 4 == 0 -> swizzle pass-invariant
  int awbase = arow * 32 + (((ac8 >> 1) ^ ((arow >> 1) & 3)) << 3) + (ac8 & 1) * 4;

  // ---- B staging map (global_load_lds, pre-swizzled source) ----
  // wave w fills 1KB chunks cidx = 2w, 2w+1 of each 8KB plane.
  int cidx0 = w * 2, cidx1 = w * 2 + 1;
  int r0 = cidx0 * 16 + (lane >> 2);
  int r1 = cidx1 * 16 + (lane >> 2);
  int lg0 = ((lane & 3) ^ ((r0 >> 1) & 3)) * 8;
  int lg1 = ((lane & 3) ^ ((r1 >> 1) & 3)) * 8;
  const u16* Bh0 = Wt_hi + (size_t)(n0 + r0) * Ee + lg0;
  const u16* Bh1 = Wt_hi + (size_t)(n0 + r1) * Ee + lg1;
  const u16* Bl0 = Wt_lo + (size_t)(n0 + r0) * Ee + lg0;
  const u16* Bl1 = Wt_lo + (size_t)(n0 + r1) * Ee + lg1;
  int bws0 = cidx0 * 512, bws1 = cidx1 * 512;   // u16 LDS offsets (wave-uniform)

  // ---- prologue: stage kt=0 into buffer 0 ----
  {
    glds16(Bh0, &BhS[bws0]);
    glds16(Bh1, &BhS[bws1]);
    glds16(Bl0, &BlS[bws0]);
    glds16(Bl1, &BlS[bws1]);
    float4 av[8];
#pragma unroll
    for (int p = 0; p < 8; ++p) av[p] = Abase[(size_t)(32 * p) * (Ee / 4)];
#pragma unroll
    for (int p = 0; p < 8; ++p)
      *(uint2*)&Ah[awbase + 1024 * p] =
          make_uint2(pack2h(av[p].x, av[p].y), pack2h(av[p].z, av[p].w));
    __syncthreads();   // drains vmcnt(0)+lgkmcnt(0): buffer 0 ready
  }

#pragma unroll 2
  for (int kt = 0; kt < 32; ++kt) {
    int curA = (kt & 1) * 8192, nxtA = 8192 - curA;
    int curB = (kt & 1) * 4096, nxtB = 4096 - curB;
    float4 av[8];
    if (kt < 31) {
      // issue next tile's loads BEFORE this tile's MFMAs (latency hides under compute)
#pragma unroll
      for (int p = 0; p < 8; ++p)
        av[p] = Abase[(size_t)(32 * p) * (Ee / 4) + (kt + 1) * 8];
      size_t ko = (size_t)(kt + 1) * 32;
      glds16(Bh0 + ko, &BhS[nxtB + bws0]);
      glds16(Bh1 + ko, &BhS[nxtB + bws1]);
      glds16(Bl0 + ko, &BlS[nxtB + bws0]);
      glds16(Bl1 + ko, &BlS[nxtB + bws1]);
    }

    f16x8 aF[8];
#pragma unroll
    for (int i = 0; i < 8; ++i)
      aF[i] = *(const f16x8*)&Ah[curA + (wm + i * 16 + c) * 32 + fch];

    __builtin_amdgcn_s_setprio(1);
#pragma unroll
    for (int j = 0; j < 4; ++j) {
      f16x8 bH = *(const f16x8*)&BhS[curB + (wn + j * 16 + c) * 32 + fch];
      f16x8 bL = *(const f16x8*)&BlS[curB + (wn + j * 16 + c) * 32 + fch];
#pragma unroll
      for (int i = 0; i < 8; ++i) {
        acc[i][j] = __builtin_amdgcn_mfma_f32_16x16x32_f16(aF[i], bH, acc[i][j], 0, 0, 0);
        acc[i][j] = __builtin_amdgcn_mfma_f32_16x16x32_f16(aF[i], bL, acc[i][j], 0, 0, 0);
      }
    }
    __builtin_amdgcn_s_setprio(0);

    if (kt < 31) {
      // consume the early A loads (compiler inserts the counted vmcnt wait)
#pragma unroll
      for (int p = 0; p < 8; ++p)
        *(uint2*)&Ah[nxtA + awbase + 1024 * p] =
            make_uint2(pack2h(av[p].x, av[p].y), pack2h(av[p].z, av[p].w));
    }
    // single barrier per K-step: drains B glds (vmcnt) + A ds_writes (lgkm);
    // safe: buf^1 writes only touch data all waves finished reading before
    // the PREVIOUS barrier.
    __syncthreads();
  }

  // epilogue: z -> tanh -> store bf16 ht; fused score partial (ctx dot)
  int bidx = m0 >> 11;                   // T = 2048; 256-row tile stays in one batch
  float ctxv[4], biasv[4];
#pragma unroll
  for (int j = 0; j < 4; ++j) {
    int col = n0 + wn + j * 16 + c;
    ctxv[j]  = ctx[bidx * Ee + col];
    biasv[j] = bias[col];
  }
#pragma unroll
  for (int i = 0; i < 8; ++i) {
#pragma unroll
    for (int r = 0; r < 4; ++r) {
      int rowG = m0 + wm + i * 16 + q * 4 + r;   // C/D: row=(lane>>4)*4+reg, col=lane&15
      u16* hrow = ht + (size_t)rowG * Ee + n0 + wn + c;
      float s = 0.f;
#pragma unroll
      for (int j = 0; j < 4; ++j) {
        float h = tanh_fast(acc[i][j][r] + biasv[j]);
        __hip_bfloat16 hb = __float2bfloat16(h);
        hrow[j * 16] = *(u16*)&hb;
        s += h * ctxv[j];
      }
      s += __shfl_xor(s, 1); s += __shfl_xor(s, 2);
      s += __shfl_xor(s, 4); s += __shfl_xor(s, 8);
      if (c == 0) atomicAdd(&scores[rowG], s);
    }
  }
}

// ---------------- K2: softmax over T per batch row ----------------
__global__ __launch_bounds__(256) void softmax_t(const float* __restrict__ scores,
                                                 float* __restrict__ at) {
  __shared__ float red[256];
  int b = blockIdx.x, tid = threadIdx.x;
  float v[8];
  float mx = -3.0e38f;
#pragma unroll
  for (int i = 0; i < 8; ++i) {
    v[i] = scores[b * Tt + i * 256 + tid];
    mx = fmaxf(mx, v[i]);
  }
  red[tid] = mx; __syncthreads();
  for (int s = 128; s > 0; s >>= 1) {
    if (tid < s) red[tid] = fmaxf(red[tid], red[tid + s]);
    __syncthreads();
  }
  mx = red[0]; __syncthreads();
  float sum = 0.f;
#pragma unroll
  for (int i = 0; i < 8; ++i) { v[i] = __expf(v[i] - mx); sum += v[i]; }
  red[tid] = sum; __syncthreads();
  for (int s = 128; s > 0; s >>= 1) {
    if (tid < s) red[tid] += red[tid + s];
    __syncthreads();
  }
  float inv = 1.0f / red[0];
#pragma unroll
  for (int i = 0; i < 8; ++i) at[b * Tt + i * 256 + tid] = v[i] * inv;
}

// ---------------- K3: partial[b,tc,e] = sum_{t in chunk} at[b,t] * ht[b,t,e] ----------------
__global__ __launch_bounds__(256) void weighted_sum(const u16* __restrict__ ht,
                                                    const float* __restrict__ at,
                                                    float* __restrict__ part) {
  __shared__ float ats[64];
  int bx = blockIdx.x;
  int b = bx >> 5, tc = bx & 31;
  int tid = threadIdx.x;
  if (tid < 64) ats[tid] = at[b * Tt + tc * 64 + tid];
  __syncthreads();
  int e0 = tid * 4;
  const u16* base = ht + (size_t)(b * Tt + tc * 64) * Ee + e0;
  float s0 = 0.f, s1 = 0.f, s2 = 0.f, s3 = 0.f;
#pragma unroll 4
  for (int t = 0; t < 64; ++t) {
    float a = ats[t];
    uint2 u = *(const uint2*)(base + (size_t)t * Ee);
    s0 += a * __uint_as_float(u.x << 16);
    s1 += a * __uint_as_float(u.x & 0xffff0000u);
    s2 += a * __uint_as_float(u.y << 16);
    s3 += a * __uint_as_float(u.y & 0xffff0000u);
  }
  float4 out4 = make_float4(s0, s1, s2, s3);
  *(float4*)(part + ((size_t)(b * 32 + tc) * Ee + e0)) = out4;
}

// ---------------- K4: out[b,e] = sum_tc part[b,tc,e] ----------------
__global__ __launch_bounds__(256) void reduce_part(const float* __restrict__ part,
                                                   float* __restrict__ out) {
  int b = blockIdx.x, tid = threadIdx.x;
  float4 s = make_float4(0.f, 0.f, 0.f, 0.f);
#pragma unroll
  for (int tc = 0; tc < 32; ++tc) {
    float4 p = ((const float4*)(part + (size_t)(b * 32 + tc) * Ee))[tid];
    s.x += p.x; s.y += p.y; s.z += p.z; s.w += p.w;
  }
  ((float4*)(out + (size_t)b * Ee))[tid] = s;
}

extern "C" void kernel_launch(void* const* d_in, const int* in_sizes, int n_in,
                              void* d_out, int out_size, void* d_ws, size_t ws_size,
                              hipStream_t stream) {
  const float* enc  = (const float*)d_in[0];
  const float* ctx  = (const float*)d_in[1];
  const float* W    = (const float*)d_in[2];
  const float* bias = (const float*)d_in[3];
  float* out = (float*)d_out;

  char* ws = (char*)d_ws;
  u16* Wt_hi = (u16*)(ws);
  u16* Wt_lo = (u16*)(ws + (size_t)2 * 1024 * 1024);
  u16* ht    = (u16*)(ws + (size_t)4 * 1024 * 1024);
  float* scores = (float*)(ws + (size_t)4 * 1024 * 1024 + (size_t)Mm * Ee * 2);
  float* at     = scores + Mm;
  // part reuses the Wt region (dead after the GEMM): 32*32*1024 fp32 = 4 MB
  float* part   = (float*)ws;

  hipMemsetAsync(scores, 0, (size_t)Mm * sizeof(float), stream);

  wt_convert<<<dim3(32, 32), dim3(32, 8), 0, stream>>>(W, Wt_hi, Wt_lo);
  gemm_tanh_score<<<dim3(2048), dim3(256), 0, stream>>>(enc, ctx, bias, Wt_hi, Wt_lo, ht, scores);
  softmax_t<<<dim3(32), dim3(256), 0, stream>>>(scores, at);
  weighted_sum<<<dim3(1024), dim3(256), 0, stream>>>(ht, at, part);
  reduce_part<<<dim3(32), dim3(256), 0, stream>>>(part, out);
}